// Round 7
// baseline (588.617 us; speedup 1.0000x reference)
//
#include <hip/hip_runtime.h>
#include <math.h>

// EGAT GNN forward — round 15 (4th resubmit; all prior benches hit
// GPUAcquisitionTimeout, kernel never ran): original-order score kernel +
// scatter-to-CSR.
// R14 post-mortem: 512-thread score blocks worked (score_frag left the top-5),
// but k_emit_perm became the #1 dispatch (59us, 175MB at 3TB/s) -- the 82MB
// efeat2 row-gather + 41MB permuted-bf16 write was a whole extra pass over
// the biggest tensor. Fix: scores are per-edge pure, so score_frag now runs
// in ORIGINAL edge order (coalesced fp32 ef reads + in-kernel f2b, direct
// src/dst) and scatters its 16B score row to scv[pos[row]] (inverse perm).
// The permute kernel shrinks to src/masks/pos (~12MB). node_fused unchanged
// (same CSR order, same accumulation order -> bit-identical output).
#define NN 50000      // N_NODES
#define NE 320000     // N_EDGES
#define BATCH 4096

typedef __bf16 bf16x8 __attribute__((ext_vector_type(8)));
typedef float floatx4 __attribute__((ext_vector_type(4)));
typedef unsigned short ushort;
typedef unsigned int uint;

__device__ __forceinline__ float lrelu02(float x) { return x > 0.f ? x : 0.2f * x; }
__device__ __forceinline__ float b2f(ushort h) { return __uint_as_float(((uint)h) << 16); }
__device__ __forceinline__ float b2f_lo(uint u) { return __uint_as_float(u << 16); }
__device__ __forceinline__ float b2f_hi(uint u) { return __uint_as_float(u & 0xffff0000u); }
__device__ __forceinline__ ushort f2b(float x) {
    uint u = __float_as_uint(x);
    return (ushort)((u + 0x7fffu + ((u >> 16) & 1u)) >> 16);  // RNE
}
__device__ __forceinline__ uint pk2(float a, float b) {
    return (uint)f2b(a) | ((uint)f2b(b) << 16);
}

// ---------------------------------------------------------------------------
// Transposed score kernel, original edge order. Per wave: 16 edges. A operand
// = weights [we|wni|wnj] (128 f-dims x KTOT), LDS, fragment-ordered, staged
// once per block. B operand = [ef | h[src] | h[dst]] per-lane 16B fragments;
// ef read coalesced fp32 + in-lane RNE convert (R12-proven, 68 VGPR). All
// global loads issued before the single barrier. Scores scattered to CSR
// position pos[row] for node_fused. 512 threads/block: LDS-limited 3
// blocks/CU -> 24 waves/CU.
// acc[c][r] = f[fdim=16c+quad*4+r] of edge l16 (fp32, pre-lrelu).
// ---------------------------------------------------------------------------
template <int GLOB>
__global__ __launch_bounds__(512, 6) void score_frag(
    const float* __restrict__ ef,       // E x (GLOB?64:16) fp32, original order
    const ushort* __restrict__ Bfrag,   // fragment-ordered weights, 128*KTOT
    const ushort* __restrict__ hb,      // N x 64 bf16 layer input
    const int* __restrict__ srcv, const int* __restrict__ dstv,
    const int* __restrict__ pos,        // original idx -> CSR position
    const float* __restrict__ attn, float* __restrict__ scv)
{
    constexpr int KTOT = GLOB ? 192 : 160;
    constexpr int NR = KTOT / 32;        // k-rounds: 6 / 5
    constexpr int EFR = GLOB ? 2 : 1;    // ef fragment rounds
    constexpr int LDA = GLOB ? 64 : 16;
    __shared__ __align__(16) ushort As[128 * KTOT];
    const int tid = threadIdx.x;
    const int w = tid >> 6, lane = tid & 63;
    const int quad = lane >> 4, l16 = lane & 15;
    const int row = (blockIdx.x << 7) + 16 * w + l16;   // original edge index

    const int s_n = srcv[row];
    const int d_n = dstv[row];
    const int prow = pos[row];

    // edge-data fragments (B operand), all issued before the barrier
    bf16x8 bfr[NR];
#pragma unroll
    for (int rnd = 0; rnd < EFR; rnd++) {
        uint4 av = make_uint4(0u, 0u, 0u, 0u);
        int k0 = rnd * 32 + quad * 8;
        if (GLOB || quad < 2) {          // loc: cols >=16 are zero-pad
            const float* ap = ef + (size_t)row * LDA + k0;
            float4 f0 = *(const float4*)ap;
            float4 f1 = *(const float4*)(ap + 4);
            av.x = pk2(f0.x, f0.y);
            av.y = pk2(f0.z, f0.w);
            av.z = pk2(f1.x, f1.y);
            av.w = pk2(f1.z, f1.w);
        }
        *(uint4*)&bfr[rnd] = av;
    }
#pragma unroll
    for (int rr = 0; rr < 2; rr++)
        bfr[EFR + rr] = *(const bf16x8*)(hb + (size_t)s_n * 64 + rr * 32 + quad * 8);
#pragma unroll
    for (int rr = 0; rr < 2; rr++)
        bfr[EFR + 2 + rr] = *(const bf16x8*)(hb + (size_t)d_n * 64 + rr * 32 + quad * 8);

    // stage fragment-ordered weights (straight copy, once per block)
    for (int i = tid; i < 128 * KTOT / 8; i += 512)
        *(uint4*)(As + (size_t)i * 8) = *(const uint4*)(Bfrag + (size_t)i * 8);
    __syncthreads();

    floatx4 acc[8];
#pragma unroll
    for (int c = 0; c < 8; c++)
#pragma unroll
        for (int r = 0; r < 4; r++) acc[c][r] = 0.f;

#pragma unroll
    for (int rnd = 0; rnd < NR; rnd++) {
#pragma unroll
        for (int c = 0; c < 8; c++) {
            bf16x8 afr = *(const bf16x8*)(As + ((size_t)(c * NR + rnd) * 64 + lane) * 8);
            acc[c] = __builtin_amdgcn_mfma_f32_16x16x32_bf16(afr, bfr[rnd], acc[c], 0, 0, 0);
        }
    }

    // epilogue: in-lane attn dot (lane owns 32 f-dims of its edge)
    float ph[4] = {0.f, 0.f, 0.f, 0.f};
#pragma unroll
    for (int c = 0; c < 8; c++) {
        int fbase = 16 * c + quad * 4;
        float4 at4 = *(const float4*)(attn + fbase);    // attn flat 128
        float v = lrelu02(acc[c][0]) * at4.x;
        v = fmaf(lrelu02(acc[c][1]), at4.y, v);
        v = fmaf(lrelu02(acc[c][2]), at4.z, v);
        v = fmaf(lrelu02(acc[c][3]), at4.w, v);
        ph[fbase >> 5] += v;
    }
#pragma unroll
    for (int h = 0; h < 4; h++) {
        ph[h] += __shfl_xor(ph[h], 16);
        ph[h] += __shfl_xor(ph[h], 32);
    }
    if (quad == 0)
        *(float4*)(scv + (size_t)prow * 4) = make_float4(ph[0], ph[1], ph[2], ph[3]);
}

// ---------------------------------------------------------------------------
// Aggregation GEMM (R8 skeleton): z (M x 256 bf16) @ Bfold^T -> act -> M x 64.
// ---------------------------------------------------------------------------
__global__ __launch_bounds__(256) void gemm_agg(
    const ushort* __restrict__ A, int M,
    const ushort* __restrict__ Bt,    // 64 x 256
    const float* __restrict__ bias, int act,
    ushort* __restrict__ outb)
{
    __shared__ __align__(16) ushort As[64 * 32];
    __shared__ __align__(16) ushort Bs[64 * 32];
    const int tid = threadIdx.x;
    const int row0 = blockIdx.x << 6;
    const int w = tid >> 6, lane = tid & 63;
    const int quad = lane >> 4, l16 = lane & 15;
    const int arow = tid >> 2, c0 = (tid & 3) << 3;
    const int agrow = row0 + arow;

    floatx4 acc[4];
#pragma unroll
    for (int c = 0; c < 4; c++)
#pragma unroll
        for (int r = 0; r < 4; r++) acc[c][r] = 0.f;

    for (int kt = 0; kt < 256; kt += 32) {
        uint4 av = make_uint4(0u, 0u, 0u, 0u);
        if (agrow < M)
            av = *(const uint4*)(A + (size_t)agrow * 256 + kt + c0);
        *(uint4*)(As + arow * 32 + c0) = av;
        {
            int bn = tid >> 2, bk = (tid & 3) << 3;
            *(uint4*)(Bs + bn * 32 + bk) = *(const uint4*)(Bt + (size_t)bn * 256 + kt + bk);
        }
        __syncthreads();
        bf16x8 af = *(const bf16x8*)(As + (16 * w + l16) * 32 + quad * 8);
#pragma unroll
        for (int c = 0; c < 4; c++) {
            bf16x8 bfv = *(const bf16x8*)(Bs + (16 * c + l16) * 32 + quad * 8);
            acc[c] = __builtin_amdgcn_mfma_f32_16x16x32_bf16(af, bfv, acc[c], 0, 0, 0);
        }
        if (kt + 32 < 256) __syncthreads();
    }
#pragma unroll
    for (int r = 0; r < 4; r++) {
        int gr = row0 + 16 * w + quad * 4 + r;
        if (gr < M) {
#pragma unroll
            for (int c = 0; c < 4; c++) {
                int col = 16 * c + l16;
                float v = acc[c][r] + bias[col];
                if (act == 0) v = v > 0.f ? v : (__expf(v) - 1.f);
                else          v = v > 0.f ? v : 0.01f * v;
                outb[(size_t)gr * 64 + col] = f2b(v);
            }
        }
    }
}

// ---------------------------------------------------------------------------
// Deterministic CSR build: histogram -> scan -> atomic rank scatter (eidx only)
// -> per-node insertion sort (original-index order) -> coalesced emit.
// ---------------------------------------------------------------------------
__global__ void k_count(const int* __restrict__ dst, int* __restrict__ deg, int E)
{
    for (int i = blockIdx.x * blockDim.x + threadIdx.x; i < E; i += gridDim.x * blockDim.x)
        atomicAdd(&deg[dst[i]], 1);
}

__global__ __launch_bounds__(256) void scan_local(
    const int* __restrict__ deg, int* __restrict__ rowptr, int* __restrict__ partials, int N)
{
    __shared__ int sd[256];
    int tid = threadIdx.x;
    int i = blockIdx.x * 256 + tid;
    int v = (i < N) ? deg[i] : 0;
    sd[tid] = v; __syncthreads();
#pragma unroll
    for (int off = 1; off < 256; off <<= 1) {
        int t = (tid >= off) ? sd[tid - off] : 0;
        __syncthreads();
        sd[tid] += t;
        __syncthreads();
    }
    if (i < N) rowptr[i] = sd[tid] - v;
    if (tid == 255) partials[blockIdx.x] = sd[255];
}

__global__ __launch_bounds__(256) void scan_partials(int* __restrict__ partials, int nb)
{
    __shared__ int sd[256];
    int tid = threadIdx.x;
    int v = (tid < nb) ? partials[tid] : 0;
    sd[tid] = v; __syncthreads();
#pragma unroll
    for (int off = 1; off < 256; off <<= 1) {
        int t = (tid >= off) ? sd[tid - off] : 0;
        __syncthreads();
        sd[tid] += t;
        __syncthreads();
    }
    if (tid < nb) partials[tid] = sd[tid] - v;
}

__global__ void scan_add(int* __restrict__ rowptr, const int* __restrict__ partials, int N, int E)
{
    int i = blockIdx.x * 256 + threadIdx.x;
    if (i < N) rowptr[i] += partials[i >> 8];
    if (i == 0) rowptr[N] = E;
}

__global__ void k_scatter(const int* __restrict__ dst, const int* __restrict__ rowptr,
                          int* __restrict__ cnt, int* __restrict__ eidx, int E)
{
    for (int i = blockIdx.x * blockDim.x + threadIdx.x; i < E; i += gridDim.x * blockDim.x) {
        int d = dst[i];
        int p = rowptr[d] + atomicAdd(&cnt[d], 1);
        eidx[p] = i;
    }
}

// one thread per node: insertion-sort its bucket ascending (deterministic,
// matches reference's index-order segment sums). Avg degree 6.4.
__global__ void k_sort_buckets(const int* __restrict__ rowptr, int* __restrict__ eidx, int N)
{
    int n = blockIdx.x * blockDim.x + threadIdx.x;
    if (n >= N) return;
    int beg = rowptr[n], end = rowptr[n + 1];
    for (int i = beg + 1; i < end; i++) {
        int v = eidx[i];
        int j = i - 1;
        while (j >= beg && eidx[j] > v) { eidx[j + 1] = eidx[j]; j--; }
        eidx[j + 1] = v;
    }
}

// small permute: per CSR position p, pull src/masks (L2-resident gathers) and
// record inverse permutation pos[e]=p for the score kernels' scatter.
__global__ void k_perm_small(const int* __restrict__ eidx, const int* __restrict__ src,
                             const float* __restrict__ m1, const float* __restrict__ m2,
                             int* __restrict__ srcp, float* __restrict__ m1p,
                             float* __restrict__ m2p, int* __restrict__ pos, int E)
{
    int p = blockIdx.x * blockDim.x + threadIdx.x;
    if (p < E) {
        int e = eidx[p];
        srcp[p] = src[e];
        m1p[p] = m1[e];
        m2p[p] = m2[e];
        pos[e] = p;
    }
}

__global__ void k_cvt(const float* __restrict__ in, ushort* __restrict__ out, int n)
{
    for (int i = blockIdx.x * blockDim.x + threadIdx.x; i < n; i += gridDim.x * blockDim.x)
        out[i] = f2b(in[i]);
}

// ---------------------------------------------------------------------------
// Weight prep. Bsc[e] = fragment-ordered [we|wni|wnj] for the transposed
// score kernel: out index o -> j=o&7, lane=(o>>3)&63, t=o>>9, c=t/NR,
// rnd=t%NR; m=16c+(lane&15), k=32rnd+(lane>>4)*8+j.
// ---------------------------------------------------------------------------
__global__ void k_prep_score_all(const float* __restrict__ loc_we, const float* __restrict__ glob_we,
                                 const float* __restrict__ loc_wni, const float* __restrict__ glob_wni,
                                 const float* __restrict__ loc_wnj, const float* __restrict__ glob_wnj,
                                 ushort* __restrict__ B)   // 4 x 24576 slots
{
    int idx = blockIdx.x * 256 + threadIdx.x;   // 4*24576 = 98304
    if (idx >= 4 * 24576) return;
    int e = idx / 24576, rem = idx % 24576;
    int layer = e >> 1, gl = e & 1;
    int KTOT = gl ? 192 : 160;
    int NR = KTOT / 32;
    int ef_end = gl ? 64 : 32;
    int ef_real = gl ? 64 : 16;
    if (rem >= 128 * KTOT) return;
    int j = rem & 7, lane = (rem >> 3) & 63, t = rem >> 9;
    int c = t / NR, rnd = t % NR;
    int m = 16 * c + (lane & 15);
    int k = 32 * rnd + (lane >> 4) * 8 + j;
    const float* we  = (gl ? glob_we  + layer * 64 * 128 : loc_we  + layer * 16 * 128);
    const float* wni = (gl ? glob_wni : loc_wni) + layer * 64 * 128;
    const float* wnj = (gl ? glob_wnj : loc_wnj) + layer * 64 * 128;
    float v;
    if (k < ef_end)            v = (k < ef_real) ? we[k * 128 + m] : 0.f;
    else if (k < ef_end + 64)  v = wni[(k - ef_end) * 128 + m];
    else                       v = wnj[(k - ef_end - 64) * 128 + m];
    B[e * 24576 + rem] = f2b(v);
}

// W'[h*64+i, j] = sum_k wnode[i, h*64+k] * aggw[h*64+k, j]; stored transposed (64 x 256)
__global__ void k_fold_all(const float* __restrict__ loc_wnode, const float* __restrict__ agg1_w,
                           const float* __restrict__ glob_wnode, const float* __restrict__ agg2_w,
                           ushort* __restrict__ B)  // 4 x (64 x 256)
{
    int e = blockIdx.x >> 6;
    int idx = (blockIdx.x & 63) * 256 + threadIdx.x;  // 16384
    int layer = e >> 1, gl = e & 1;
    const float* wnode = (gl ? glob_wnode : loc_wnode) + layer * 64 * 256;
    const float* aggw  = (gl ? agg2_w : agg1_w) + layer * 256 * 64;
    int j = idx >> 8, col = idx & 255;
    int h = col >> 6, ii = col & 63;
    float s = 0.f;
#pragma unroll 8
    for (int k = 0; k < 64; k++)
        s = fmaf(wnode[ii * 256 + h * 64 + k], aggw[(h * 64 + k) * 64 + j], s);
    B[e * 16384 + j * 256 + col] = f2b(s);
}

// ---------------------------------------------------------------------------
// Node kernel, zero cross-lane ops: one 16-lane group per node (all 4 heads),
// 16 groups per block, grid NN/16.
// ---------------------------------------------------------------------------
__global__ __launch_bounds__(256) void node_fused(
    const float* __restrict__ scv,      // E x 4 fp32 (CSR order)
    const int* __restrict__ rowptr, const int* __restrict__ srcp,
    const float* __restrict__ maskp,
    const ushort* __restrict__ hsrc,    // N x 64 bf16 (layer input)
    ushort* __restrict__ zb)            // N x 256 bf16
{
    int tid = threadIdx.x;
    int n = (blockIdx.x << 4) | (tid >> 4);   // 16 groups/block, one node each
    int sl = tid & 15;
    int beg = rowptr[n], end = rowptr[n + 1];
    float l0 = 0.f, l1 = 0.f, l2 = 0.f, l3 = 0.f;
    float acc[4][4] = {};
#pragma unroll 2
    for (int i = beg; i < end; i++) {
        float4 s4 = *(const float4*)(scv + (size_t)i * 4);   // broadcast in group
        float mk = maskp[i];
        int s = srcp[i];
        uint2 hvv = *(const uint2*)(hsrc + (size_t)s * 64 + sl * 4);  // 128B/group
        float t0 = __expf(s4.x), t1 = __expf(s4.y), t2 = __expf(s4.z), t3 = __expf(s4.w);
        l0 += t0; l1 += t1; l2 += t2; l3 += t3;
        float a0 = t0 * mk, a1 = t1 * mk, a2 = t2 * mk, a3 = t3 * mk;
        float hv[4] = { b2f_lo(hvv.x), b2f_hi(hvv.x), b2f_lo(hvv.y), b2f_hi(hvv.y) };
#pragma unroll
        for (int c = 0; c < 4; c++) {
            acc[0][c] = fmaf(a0, hv[c], acc[0][c]);
            acc[1][c] = fmaf(a1, hv[c], acc[1][c]);
            acc[2][c] = fmaf(a2, hv[c], acc[2][c]);
            acc[3][c] = fmaf(a3, hv[c], acc[3][c]);
        }
    }
    float inv[4] = { 1.f / (l0 + 1e-9f), 1.f / (l1 + 1e-9f),
                     1.f / (l2 + 1e-9f), 1.f / (l3 + 1e-9f) };
#pragma unroll
    for (int h = 0; h < 4; h++) {
        uint2 o;
        o.x = (uint)f2b(acc[h][0] * inv[h]) | ((uint)f2b(acc[h][1] * inv[h]) << 16);
        o.y = (uint)f2b(acc[h][2] * inv[h]) | ((uint)f2b(acc[h][3] * inv[h]) << 16);
        *(uint2*)(zb + (size_t)n * 256 + h * 64 + sl * 4) = o;
    }
}

// ---------------------------------------------------------------------------
// Final MLP heads. One wave per batch row.
// ---------------------------------------------------------------------------
__global__ __launch_bounds__(256) void final_ui(
    const ushort* __restrict__ s0, const ushort* __restrict__ s1,
    const int* __restrict__ uidx, const int* __restrict__ iidx,
    const float* __restrict__ w1, const float* __restrict__ b1,
    const float* __restrict__ w2, const float* __restrict__ b2, float* __restrict__ out)
{
    __shared__ float xs[4][256];
    int tid = threadIdx.x, wid = tid >> 6, lane = tid & 63;
    int r = (blockIdx.x << 2) + wid;
    int u = uidx[r], it = iidx[r];
    xs[wid][lane]       = b2f(s0[(size_t)u * 64 + lane]);
    xs[wid][64 + lane]  = b2f(s1[(size_t)u * 64 + lane]);
    xs[wid][128 + lane] = b2f(s0[(size_t)it * 64 + lane]);
    xs[wid][192 + lane] = b2f(s1[(size_t)it * 64 + lane]);
    __syncthreads();
    int c = lane << 1;
    float a0 = b1[c], a1 = b1[c + 1];
    for (int k = 0; k < 256; k++) {
        float xv = xs[wid][k];
        float2 wv = *(const float2*)(w1 + (size_t)k * 128 + c);
        a0 = fmaf(xv, wv.x, a0);
        a1 = fmaf(xv, wv.y, a1);
    }
    a0 = fmaxf(a0, 0.f);
    a1 = fmaxf(a1, 0.f);
    float2 w2v = *(const float2*)(w2 + c);
    float p = a0 * w2v.x + a1 * w2v.y;
#pragma unroll
    for (int mm = 1; mm < 64; mm <<= 1) p += __shfl_xor(p, mm);
    if (lane == 0) out[r] = 1.f / (1.f + __expf(-(p + b2[0])));
}

__global__ __launch_bounds__(256) void final_sg(
    const ushort* __restrict__ s0, const ushort* __restrict__ s1,
    const int* __restrict__ gidx,
    const float* __restrict__ w1, const float* __restrict__ b1,
    const float* __restrict__ w2, const float* __restrict__ b2, float* __restrict__ out)
{
    __shared__ float xs[4][128];
    int tid = threadIdx.x, wid = tid >> 6, lane = tid & 63;
    int r = (blockIdx.x << 2) + wid;
    int n = gidx[r];
    xs[wid][lane]      = b2f(s0[(size_t)n * 64 + lane]);
    xs[wid][64 + lane] = b2f(s1[(size_t)n * 64 + lane]);
    __syncthreads();
    int c = lane << 1;
    float a0 = b1[c], a1 = b1[c + 1];
    for (int k = 0; k < 128; k++) {
        float xv = xs[wid][k];
        float2 wv = *(const float2*)(w1 + (size_t)k * 128 + c);
        a0 = fmaf(xv, wv.x, a0);
        a1 = fmaf(xv, wv.y, a1);
    }
    a0 = fmaxf(a0, 0.f);
    a1 = fmaxf(a1, 0.f);
    float2 w2v = *(const float2*)(w2 + c);
    float p = a0 * w2v.x + a1 * w2v.y;
#pragma unroll
    for (int mm = 1; mm < 64; mm <<= 1) p += __shfl_xor(p, mm);
    if (lane == 0) out[r] = 1.f / (1.f + __expf(-(p + b2[0])));
}

// ---------------------------------------------------------------------------
extern "C" void kernel_launch(void* const* d_in, const int* in_sizes, int n_in,
                              void* d_out, int out_size, void* d_ws, size_t ws_size,
                              hipStream_t stream)
{
    const float* x       = (const float*)d_in[0];
    const float* efeat   = (const float*)d_in[1];
    const float* efeat2  = (const float*)d_in[2];
    const float* mask1   = (const float*)d_in[3];
    const float* mask2   = (const float*)d_in[4];
    const int*   src     = (const int*)d_in[5];
    const int*   dst     = (const int*)d_in[6];
    const int*   uidx    = (const int*)d_in[7];
    const int*   iidx    = (const int*)d_in[8];
    const int*   gidx    = (const int*)d_in[9];
    const float* loc_wni = (const float*)d_in[10];
    const float* loc_wnj = (const float*)d_in[11];
    const float* loc_we  = (const float*)d_in[12];
    const float* loc_attn= (const float*)d_in[13];
    const float* loc_wnode=(const float*)d_in[14];
    const float* agg1_w  = (const float*)d_in[15];
    const float* agg1_b  = (const float*)d_in[16];
    const float* glob_wni= (const float*)d_in[17];
    const float* glob_wnj= (const float*)d_in[18];
    const float* glob_we = (const float*)d_in[19];
    const float* glob_attn=(const float*)d_in[20];
    const float* glob_wnode=(const float*)d_in[21];
    const float* agg2_w  = (const float*)d_in[22];
    const float* agg2_b  = (const float*)d_in[23];
    const float* w1_ui   = (const float*)d_in[24];
    const float* b1_ui   = (const float*)d_in[25];
    const float* w1_sg   = (const float*)d_in[26];
    const float* b1_sg   = (const float*)d_in[27];
    const float* w2_ui   = (const float*)d_in[28];
    const float* b2_ui   = (const float*)d_in[29];
    const float* w2_sg   = (const float*)d_in[30];
    const float* b2_sg   = (const float*)d_in[31];

    // workspace carve (all offsets 256B-aligned)
    char* wsp = (char*)d_ws;
    auto carve = [&](size_t bytes) { char* p = wsp; wsp += (bytes + 255) & ~(size_t)255; return p; };
    ushort* zb    = (ushort*)carve((size_t)NN * 256 * 2);
    ushort* hb[5];
    for (int i = 0; i < 5; i++) hb[i] = (ushort*)carve((size_t)NN * 64 * 2);
    float*  scv   = (float*)carve((size_t)NE * 16);
    float*  m1p   = (float*)carve((size_t)NE * 4);
    float*  m2p   = (float*)carve((size_t)NE * 4);
    int*    srcp  = (int*)carve((size_t)NE * 4);
    int*    pos   = (int*)carve((size_t)NE * 4);
    int*    eidx  = (int*)carve((size_t)NE * 4);
    ushort* Bsc   = (ushort*)carve(4 * 24576 * 2);
    ushort* Bfold = (ushort*)carve(4 * 16384 * 2);
    int* deg      = (int*)carve(NN * 4);
    int* rowptr   = (int*)carve((NN + 4) * 4);
    int* partials = (int*)carve(256 * 4);

    // ---- weight prep (state-independent) + deterministic CSR build ----
    k_prep_score_all<<<384, 256, 0, stream>>>(loc_we, glob_we, loc_wni, glob_wni,
                                              loc_wnj, glob_wnj, Bsc);
    k_fold_all<<<256, 256, 0, stream>>>(loc_wnode, agg1_w, glob_wnode, agg2_w, Bfold);
    hipMemsetAsync(deg, 0, NN * sizeof(int), stream);
    k_count<<<1280, 256, 0, stream>>>(dst, deg, NE);
    scan_local<<<196, 256, 0, stream>>>(deg, rowptr, partials, NN);
    scan_partials<<<1, 256, 0, stream>>>(partials, 196);
    scan_add<<<196, 256, 0, stream>>>(rowptr, partials, NN, NE);
    hipMemsetAsync(deg, 0, NN * sizeof(int), stream);
    k_scatter<<<1280, 256, 0, stream>>>(dst, rowptr, deg, eidx, NE);
    k_sort_buckets<<<196, 256, 0, stream>>>(rowptr, eidx, NN);
    k_perm_small<<<1250, 256, 0, stream>>>(eidx, src, mask1, mask2,
                                           srcp, m1p, m2p, pos, NE);
    k_cvt<<<3200, 256, 0, stream>>>(x, hb[0], NN * 64);

    auto egat = [&](const ushort* hin, int e, const float* maskp, const float* attn,
                    const float* aggb, int act, ushort* hout) {
        int is_glob = e & 1;
        if (is_glob)
            score_frag<1><<<2500, 512, 0, stream>>>(efeat2, Bsc + e * 24576, hin,
                                                    src, dst, pos, attn, scv);
        else
            score_frag<0><<<2500, 512, 0, stream>>>(efeat, Bsc + e * 24576, hin,
                                                    src, dst, pos, attn, scv);
        node_fused<<<NN / 16, 256, 0, stream>>>(scv, rowptr, srcp, maskp, hin, zb);
        gemm_agg<<<782, 256, 0, stream>>>(zb, NN, Bfold + e * 16384, aggb, act, hout);
    };

    egat(hb[0], 0, m1p, loc_attn,        agg1_b,      0, hb[1]);
    egat(hb[1], 1, m2p, glob_attn,       agg2_b,      1, hb[2]);
    egat(hb[2], 2, m1p, loc_attn + 128,  agg1_b + 64, 0, hb[3]);
    egat(hb[3], 3, m2p, glob_attn + 128, agg2_b + 64, 1, hb[4]);

    float* out = (float*)d_out;
    final_sg<<<BATCH / 4, 256, 0, stream>>>(hb[2], hb[4], gidx, w1_sg, b1_sg, w2_sg, b2_sg, out);
    final_ui<<<BATCH / 4, 256, 0, stream>>>(hb[1], hb[3], uidx, iidx, w1_ui, b1_ui, w2_ui, b2_ui, out + BATCH);
}

// Round 8
// 560.794 us; speedup vs baseline: 1.0496x; 1.0496x over previous
//
#include <hip/hip_runtime.h>
#include <math.h>

// EGAT GNN forward — round 16: 32x32x16 MFMA score kernel (32 edges/wave).
// R15 post-mortem: score_frag 59us, MfmaUtil 10%, VALU 16%, HBM 18% -- cycle
// model shows the compute phase is LDS-READ bound: each 16x16x32 MFMA eats a
// 1KB A-fragment, and every wave re-reads the whole 49KB weight matrix for
// only 16 edges (16 waves x 48 x 1KB ~= 9.2K cyc of the ~13K/block-pair).
// Fix: mfma_f32_32x32x16_bf16 -- 32 edges share each A-read (A-traffic/edge
// halved), 256 edges/block (staging halved, grid 1250). ctile-at-a-time loop
// keeps one 16-reg acc live (~100 VGPR, launch_bounds(512,4)). Head h ==
// ctile c (32 f-dims) -> single shfl_xor(32) epilogue. scv now in ORIGINAL
// edge order (coalesced writes, no pos scatter; R15 showed 2x write
// amplification); node_fused reads scv[eidx[i]] -- same values, same order,
// bit-identical output; scv is L2-resident.
#define NN 50000      // N_NODES
#define NE 320000     // N_EDGES
#define BATCH 4096

typedef __bf16 bf16x8 __attribute__((ext_vector_type(8)));
typedef float floatx4 __attribute__((ext_vector_type(4)));
typedef float floatx16 __attribute__((ext_vector_type(16)));
typedef unsigned short ushort;
typedef unsigned int uint;

__device__ __forceinline__ float lrelu02(float x) { return x > 0.f ? x : 0.2f * x; }
__device__ __forceinline__ float b2f(ushort h) { return __uint_as_float(((uint)h) << 16); }
__device__ __forceinline__ float b2f_lo(uint u) { return __uint_as_float(u << 16); }
__device__ __forceinline__ float b2f_hi(uint u) { return __uint_as_float(u & 0xffff0000u); }
__device__ __forceinline__ ushort f2b(float x) {
    uint u = __float_as_uint(x);
    return (ushort)((u + 0x7fffu + ((u >> 16) & 1u)) >> 16);  // RNE
}
__device__ __forceinline__ uint pk2(float a, float b) {
    return (uint)f2b(a) | ((uint)f2b(b) << 16);
}

// ---------------------------------------------------------------------------
// 32x32x16 transposed score kernel, original edge order. Per wave: 32 edges.
// A = weights [we|wni|wnj] (128 f-dims x KTOT), LDS, fragment-ordered, staged
// once per block. B = [ef | h[src] | h[dst]]: per-lane 16B bf16 k-fragments
// (k = 16t + 8*(lane>>5) + j), edge n = lane&31. All global loads issued
// before the single barrier. ctile c == head c: acc row = (reg&3)+8*(reg>>2)
// +4*hi (m74/m101-verified C/D layout). One ctile acc live at a time.
// Coalesced scv write at original edge index.
// ---------------------------------------------------------------------------
template <int GLOB>
__global__ __launch_bounds__(512, 4) void score32(
    const float* __restrict__ ef,       // E x (GLOB?64:16) fp32, original order
    const ushort* __restrict__ Bfrag,   // fragment-ordered weights, 128*KTOT
    const ushort* __restrict__ hb,      // N x 64 bf16 layer input
    const int* __restrict__ srcv, const int* __restrict__ dstv,
    const float* __restrict__ attn, float* __restrict__ scv)
{
    constexpr int NK = GLOB ? 12 : 9;    // k-steps of 16: ef(4|1)+wni(4)+wnj(4)
    constexpr int KTOT = NK * 16;        // 192 / 144
    constexpr int EFR = GLOB ? 4 : 1;    // ef k-fragments
    constexpr int LDA = GLOB ? 64 : 16;
    __shared__ __align__(16) ushort As[128 * KTOT];
    const int tid = threadIdx.x;
    const int wid = tid >> 6, lane = tid & 63;
    const int hi = lane >> 5;            // k-half
    const int row = (blockIdx.x << 8) + (wid << 5) + (lane & 31);  // edge

    const int s_n = srcv[row];
    const int d_n = dstv[row];

    // B-operand fragments, all issued before the barrier
    bf16x8 bfr[NK];
#pragma unroll
    for (int t = 0; t < EFR; t++) {
        const float* ap = ef + (size_t)row * LDA + t * 16 + hi * 8;
        float4 f0 = *(const float4*)ap;
        float4 f1 = *(const float4*)(ap + 4);
        uint4 av;
        av.x = pk2(f0.x, f0.y); av.y = pk2(f0.z, f0.w);
        av.z = pk2(f1.x, f1.y); av.w = pk2(f1.z, f1.w);
        *(uint4*)&bfr[t] = av;
    }
#pragma unroll
    for (int t = 0; t < 4; t++)
        bfr[EFR + t] = *(const bf16x8*)(hb + (size_t)s_n * 64 + t * 16 + hi * 8);
#pragma unroll
    for (int t = 0; t < 4; t++)
        bfr[EFR + 4 + t] = *(const bf16x8*)(hb + (size_t)d_n * 64 + t * 16 + hi * 8);

    // stage fragment-ordered weights (straight copy, once per block)
    for (int i = tid; i < 128 * KTOT / 8; i += 512)
        *(uint4*)(As + (size_t)i * 8) = *(const uint4*)(Bfrag + (size_t)i * 8);
    __syncthreads();

    float ph[4];
#pragma unroll
    for (int c = 0; c < 4; c++) {        // ctile c == head c (32 f-dims)
        floatx16 acc;
#pragma unroll
        for (int r = 0; r < 16; r++) acc[r] = 0.f;
#pragma unroll
        for (int t = 0; t < NK; t++) {
            bf16x8 afr = *(const bf16x8*)(As + ((size_t)(c * NK + t) * 64 + lane) * 8);
            acc = __builtin_amdgcn_mfma_f32_32x32x16_bf16(afr, bfr[t], acc, 0, 0, 0);
        }
        // epilogue: row = (reg&3) + 8*(reg>>2) + 4*hi; attn flat 128
        float v = 0.f;
#pragma unroll
        for (int q = 0; q < 4; q++) {
            float4 at4 = *(const float4*)(attn + c * 32 + hi * 4 + q * 8);
            v = fmaf(lrelu02(acc[q * 4 + 0]), at4.x, v);
            v = fmaf(lrelu02(acc[q * 4 + 1]), at4.y, v);
            v = fmaf(lrelu02(acc[q * 4 + 2]), at4.z, v);
            v = fmaf(lrelu02(acc[q * 4 + 3]), at4.w, v);
        }
        ph[c] = v;
    }
#pragma unroll
    for (int h = 0; h < 4; h++) ph[h] += __shfl_xor(ph[h], 32);
    if (hi == 0)
        *(float4*)(scv + (size_t)row * 4) = make_float4(ph[0], ph[1], ph[2], ph[3]);
}

// ---------------------------------------------------------------------------
// Aggregation GEMM (R8 skeleton): z (M x 256 bf16) @ Bfold^T -> act -> M x 64.
// ---------------------------------------------------------------------------
__global__ __launch_bounds__(256) void gemm_agg(
    const ushort* __restrict__ A, int M,
    const ushort* __restrict__ Bt,    // 64 x 256
    const float* __restrict__ bias, int act,
    ushort* __restrict__ outb)
{
    __shared__ __align__(16) ushort As[64 * 32];
    __shared__ __align__(16) ushort Bs[64 * 32];
    const int tid = threadIdx.x;
    const int row0 = blockIdx.x << 6;
    const int w = tid >> 6, lane = tid & 63;
    const int quad = lane >> 4, l16 = lane & 15;
    const int arow = tid >> 2, c0 = (tid & 3) << 3;
    const int agrow = row0 + arow;

    floatx4 acc[4];
#pragma unroll
    for (int c = 0; c < 4; c++)
#pragma unroll
        for (int r = 0; r < 4; r++) acc[c][r] = 0.f;

    for (int kt = 0; kt < 256; kt += 32) {
        uint4 av = make_uint4(0u, 0u, 0u, 0u);
        if (agrow < M)
            av = *(const uint4*)(A + (size_t)agrow * 256 + kt + c0);
        *(uint4*)(As + arow * 32 + c0) = av;
        {
            int bn = tid >> 2, bk = (tid & 3) << 3;
            *(uint4*)(Bs + bn * 32 + bk) = *(const uint4*)(Bt + (size_t)bn * 256 + kt + bk);
        }
        __syncthreads();
        bf16x8 af = *(const bf16x8*)(As + (16 * w + l16) * 32 + quad * 8);
#pragma unroll
        for (int c = 0; c < 4; c++) {
            bf16x8 bfv = *(const bf16x8*)(Bs + (16 * c + l16) * 32 + quad * 8);
            acc[c] = __builtin_amdgcn_mfma_f32_16x16x32_bf16(af, bfv, acc[c], 0, 0, 0);
        }
        if (kt + 32 < 256) __syncthreads();
    }
#pragma unroll
    for (int r = 0; r < 4; r++) {
        int gr = row0 + 16 * w + quad * 4 + r;
        if (gr < M) {
#pragma unroll
            for (int c = 0; c < 4; c++) {
                int col = 16 * c + l16;
                float v = acc[c][r] + bias[col];
                if (act == 0) v = v > 0.f ? v : (__expf(v) - 1.f);
                else          v = v > 0.f ? v : 0.01f * v;
                outb[(size_t)gr * 64 + col] = f2b(v);
            }
        }
    }
}

// ---------------------------------------------------------------------------
// Deterministic CSR build: histogram -> scan -> atomic rank scatter (eidx only)
// -> per-node insertion sort (original-index order).
// ---------------------------------------------------------------------------
__global__ void k_count(const int* __restrict__ dst, int* __restrict__ deg, int E)
{
    for (int i = blockIdx.x * blockDim.x + threadIdx.x; i < E; i += gridDim.x * blockDim.x)
        atomicAdd(&deg[dst[i]], 1);
}

__global__ __launch_bounds__(256) void scan_local(
    const int* __restrict__ deg, int* __restrict__ rowptr, int* __restrict__ partials, int N)
{
    __shared__ int sd[256];
    int tid = threadIdx.x;
    int i = blockIdx.x * 256 + tid;
    int v = (i < N) ? deg[i] : 0;
    sd[tid] = v; __syncthreads();
#pragma unroll
    for (int off = 1; off < 256; off <<= 1) {
        int t = (tid >= off) ? sd[tid - off] : 0;
        __syncthreads();
        sd[tid] += t;
        __syncthreads();
    }
    if (i < N) rowptr[i] = sd[tid] - v;
    if (tid == 255) partials[blockIdx.x] = sd[255];
}

__global__ __launch_bounds__(256) void scan_partials(int* __restrict__ partials, int nb)
{
    __shared__ int sd[256];
    int tid = threadIdx.x;
    int v = (tid < nb) ? partials[tid] : 0;
    sd[tid] = v; __syncthreads();
#pragma unroll
    for (int off = 1; off < 256; off <<= 1) {
        int t = (tid >= off) ? sd[tid - off] : 0;
        __syncthreads();
        sd[tid] += t;
        __syncthreads();
    }
    if (tid < nb) partials[tid] = sd[tid] - v;
}

__global__ void scan_add(int* __restrict__ rowptr, const int* __restrict__ partials, int N, int E)
{
    int i = blockIdx.x * 256 + threadIdx.x;
    if (i < N) rowptr[i] += partials[i >> 8];
    if (i == 0) rowptr[N] = E;
}

__global__ void k_scatter(const int* __restrict__ dst, const int* __restrict__ rowptr,
                          int* __restrict__ cnt, int* __restrict__ eidx, int E)
{
    for (int i = blockIdx.x * blockDim.x + threadIdx.x; i < E; i += gridDim.x * blockDim.x) {
        int d = dst[i];
        int p = rowptr[d] + atomicAdd(&cnt[d], 1);
        eidx[p] = i;
    }
}

// one thread per node: insertion-sort its bucket ascending (deterministic,
// matches reference's index-order segment sums). Avg degree 6.4.
__global__ void k_sort_buckets(const int* __restrict__ rowptr, int* __restrict__ eidx, int N)
{
    int n = blockIdx.x * blockDim.x + threadIdx.x;
    if (n >= N) return;
    int beg = rowptr[n], end = rowptr[n + 1];
    for (int i = beg + 1; i < end; i++) {
        int v = eidx[i];
        int j = i - 1;
        while (j >= beg && eidx[j] > v) { eidx[j + 1] = eidx[j]; j--; }
        eidx[j + 1] = v;
    }
}

// small permute: per CSR position p, pull src/masks (L2-resident gathers).
__global__ void k_perm_small(const int* __restrict__ eidx, const int* __restrict__ src,
                             const float* __restrict__ m1, const float* __restrict__ m2,
                             int* __restrict__ srcp, float* __restrict__ m1p,
                             float* __restrict__ m2p, int E)
{
    int p = blockIdx.x * blockDim.x + threadIdx.x;
    if (p < E) {
        int e = eidx[p];
        srcp[p] = src[e];
        m1p[p] = m1[e];
        m2p[p] = m2[e];
    }
}

__global__ void k_cvt(const float* __restrict__ in, ushort* __restrict__ out, int n)
{
    for (int i = blockIdx.x * blockDim.x + threadIdx.x; i < n; i += gridDim.x * blockDim.x)
        out[i] = f2b(in[i]);
}

// ---------------------------------------------------------------------------
// Weight prep for the 32x32x16 score kernel. Bsc[e] fragment order: out index
// o -> j=o&7, lane=(o>>3)&63, tf=o>>9, c=tf/NK, t=tf%NK; m=32c+(lane&31),
// k=16t+8*(lane>>5)+j. Columns: [we(ef_end)|wni(64)|wnj(64)].
// glob: NK=12 (KTOT 192); loc: NK=9 (KTOT 144, no pad).
// ---------------------------------------------------------------------------
__global__ void k_prep_score_all(const float* __restrict__ loc_we, const float* __restrict__ glob_we,
                                 const float* __restrict__ loc_wni, const float* __restrict__ glob_wni,
                                 const float* __restrict__ loc_wnj, const float* __restrict__ glob_wnj,
                                 ushort* __restrict__ B)   // 4 x 24576 slots
{
    int idx = blockIdx.x * 256 + threadIdx.x;   // 4*24576 = 98304
    if (idx >= 4 * 24576) return;
    int e = idx / 24576, rem = idx % 24576;
    int layer = e >> 1, gl = e & 1;
    int NK = gl ? 12 : 9;
    int KTOT = NK * 16;
    int ef_end = gl ? 64 : 16;
    if (rem >= 128 * KTOT) return;
    int j = rem & 7, lane = (rem >> 3) & 63, tf = rem >> 9;
    int c = tf / NK, t = tf % NK;
    int m = 32 * c + (lane & 31);
    int k = 16 * t + 8 * (lane >> 5) + j;
    const float* we  = (gl ? glob_we  + layer * 64 * 128 : loc_we  + layer * 16 * 128);
    const float* wni = (gl ? glob_wni : loc_wni) + layer * 64 * 128;
    const float* wnj = (gl ? glob_wnj : loc_wnj) + layer * 64 * 128;
    float v;
    if (k < ef_end)            v = we[k * 128 + m];
    else if (k < ef_end + 64)  v = wni[(k - ef_end) * 128 + m];
    else                       v = wnj[(k - ef_end - 64) * 128 + m];
    B[e * 24576 + rem] = f2b(v);
}

// W'[h*64+i, j] = sum_k wnode[i, h*64+k] * aggw[h*64+k, j]; stored transposed (64 x 256)
__global__ void k_fold_all(const float* __restrict__ loc_wnode, const float* __restrict__ agg1_w,
                           const float* __restrict__ glob_wnode, const float* __restrict__ agg2_w,
                           ushort* __restrict__ B)  // 4 x (64 x 256)
{
    int e = blockIdx.x >> 6;
    int idx = (blockIdx.x & 63) * 256 + threadIdx.x;  // 16384
    int layer = e >> 1, gl = e & 1;
    const float* wnode = (gl ? glob_wnode : loc_wnode) + layer * 64 * 256;
    const float* aggw  = (gl ? agg2_w : agg1_w) + layer * 256 * 64;
    int j = idx >> 8, col = idx & 255;
    int h = col >> 6, ii = col & 63;
    float s = 0.f;
#pragma unroll 8
    for (int k = 0; k < 64; k++)
        s = fmaf(wnode[ii * 256 + h * 64 + k], aggw[(h * 64 + k) * 64 + j], s);
    B[e * 16384 + j * 256 + col] = f2b(s);
}

// ---------------------------------------------------------------------------
// Node kernel: one 16-lane group per node (all 4 heads), 16 groups per block.
// Scores gathered from original-order scv via eidx (L2-resident, same CSR
// iteration order -> bit-identical accumulation).
// ---------------------------------------------------------------------------
__global__ __launch_bounds__(256) void node_fused(
    const float* __restrict__ scv,      // E x 4 fp32 (ORIGINAL edge order)
    const int* __restrict__ eidx,       // CSR position -> original edge
    const int* __restrict__ rowptr, const int* __restrict__ srcp,
    const float* __restrict__ maskp,
    const ushort* __restrict__ hsrc,    // N x 64 bf16 (layer input)
    ushort* __restrict__ zb)            // N x 256 bf16
{
    int tid = threadIdx.x;
    int n = (blockIdx.x << 4) | (tid >> 4);   // 16 groups/block, one node each
    int sl = tid & 15;
    int beg = rowptr[n], end = rowptr[n + 1];
    float l0 = 0.f, l1 = 0.f, l2 = 0.f, l3 = 0.f;
    float acc[4][4] = {};
#pragma unroll 2
    for (int i = beg; i < end; i++) {
        int ep = eidx[i];                                    // broadcast in group
        float4 s4 = *(const float4*)(scv + (size_t)ep * 4);  // L2-resident
        float mk = maskp[i];
        int s = srcp[i];
        uint2 hvv = *(const uint2*)(hsrc + (size_t)s * 64 + sl * 4);  // 128B/group
        float t0 = __expf(s4.x), t1 = __expf(s4.y), t2 = __expf(s4.z), t3 = __expf(s4.w);
        l0 += t0; l1 += t1; l2 += t2; l3 += t3;
        float a0 = t0 * mk, a1 = t1 * mk, a2 = t2 * mk, a3 = t3 * mk;
        float hv[4] = { b2f_lo(hvv.x), b2f_hi(hvv.x), b2f_lo(hvv.y), b2f_hi(hvv.y) };
#pragma unroll
        for (int c = 0; c < 4; c++) {
            acc[0][c] = fmaf(a0, hv[c], acc[0][c]);
            acc[1][c] = fmaf(a1, hv[c], acc[1][c]);
            acc[2][c] = fmaf(a2, hv[c], acc[2][c]);
            acc[3][c] = fmaf(a3, hv[c], acc[3][c]);
        }
    }
    float inv[4] = { 1.f / (l0 + 1e-9f), 1.f / (l1 + 1e-9f),
                     1.f / (l2 + 1e-9f), 1.f / (l3 + 1e-9f) };
#pragma unroll
    for (int h = 0; h < 4; h++) {
        uint2 o;
        o.x = (uint)f2b(acc[h][0] * inv[h]) | ((uint)f2b(acc[h][1] * inv[h]) << 16);
        o.y = (uint)f2b(acc[h][2] * inv[h]) | ((uint)f2b(acc[h][3] * inv[h]) << 16);
        *(uint2*)(zb + (size_t)n * 256 + h * 64 + sl * 4) = o;
    }
}

// ---------------------------------------------------------------------------
// Final MLP heads. One wave per batch row.
// ---------------------------------------------------------------------------
__global__ __launch_bounds__(256) void final_ui(
    const ushort* __restrict__ s0, const ushort* __restrict__ s1,
    const int* __restrict__ uidx, const int* __restrict__ iidx,
    const float* __restrict__ w1, const float* __restrict__ b1,
    const float* __restrict__ w2, const float* __restrict__ b2, float* __restrict__ out)
{
    __shared__ float xs[4][256];
    int tid = threadIdx.x, wid = tid >> 6, lane = tid & 63;
    int r = (blockIdx.x << 2) + wid;
    int u = uidx[r], it = iidx[r];
    xs[wid][lane]       = b2f(s0[(size_t)u * 64 + lane]);
    xs[wid][64 + lane]  = b2f(s1[(size_t)u * 64 + lane]);
    xs[wid][128 + lane] = b2f(s0[(size_t)it * 64 + lane]);
    xs[wid][192 + lane] = b2f(s1[(size_t)it * 64 + lane]);
    __syncthreads();
    int c = lane << 1;
    float a0 = b1[c], a1 = b1[c + 1];
    for (int k = 0; k < 256; k++) {
        float xv = xs[wid][k];
        float2 wv = *(const float2*)(w1 + (size_t)k * 128 + c);
        a0 = fmaf(xv, wv.x, a0);
        a1 = fmaf(xv, wv.y, a1);
    }
    a0 = fmaxf(a0, 0.f);
    a1 = fmaxf(a1, 0.f);
    float2 w2v = *(const float2*)(w2 + c);
    float p = a0 * w2v.x + a1 * w2v.y;
#pragma unroll
    for (int mm = 1; mm < 64; mm <<= 1) p += __shfl_xor(p, mm);
    if (lane == 0) out[r] = 1.f / (1.f + __expf(-(p + b2[0])));
}

__global__ __launch_bounds__(256) void final_sg(
    const ushort* __restrict__ s0, const ushort* __restrict__ s1,
    const int* __restrict__ gidx,
    const float* __restrict__ w1, const float* __restrict__ b1,
    const float* __restrict__ w2, const float* __restrict__ b2, float* __restrict__ out)
{
    __shared__ float xs[4][128];
    int tid = threadIdx.x, wid = tid >> 6, lane = tid & 63;
    int r = (blockIdx.x << 2) + wid;
    int n = gidx[r];
    xs[wid][lane]      = b2f(s0[(size_t)n * 64 + lane]);
    xs[wid][64 + lane] = b2f(s1[(size_t)n * 64 + lane]);
    __syncthreads();
    int c = lane << 1;
    float a0 = b1[c], a1 = b1[c + 1];
    for (int k = 0; k < 128; k++) {
        float xv = xs[wid][k];
        float2 wv = *(const float2*)(w1 + (size_t)k * 128 + c);
        a0 = fmaf(xv, wv.x, a0);
        a1 = fmaf(xv, wv.y, a1);
    }
    a0 = fmaxf(a0, 0.f);
    a1 = fmaxf(a1, 0.f);
    float2 w2v = *(const float2*)(w2 + c);
    float p = a0 * w2v.x + a1 * w2v.y;
#pragma unroll
    for (int mm = 1; mm < 64; mm <<= 1) p += __shfl_xor(p, mm);
    if (lane == 0) out[r] = 1.f / (1.f + __expf(-(p + b2[0])));
}

// ---------------------------------------------------------------------------
extern "C" void kernel_launch(void* const* d_in, const int* in_sizes, int n_in,
                              void* d_out, int out_size, void* d_ws, size_t ws_size,
                              hipStream_t stream)
{
    const float* x       = (const float*)d_in[0];
    const float* efeat   = (const float*)d_in[1];
    const float* efeat2  = (const float*)d_in[2];
    const float* mask1   = (const float*)d_in[3];
    const float* mask2   = (const float*)d_in[4];
    const int*   src     = (const int*)d_in[5];
    const int*   dst     = (const int*)d_in[6];
    const int*   uidx    = (const int*)d_in[7];
    const int*   iidx    = (const int*)d_in[8];
    const int*   gidx    = (const int*)d_in[9];
    const float* loc_wni = (const float*)d_in[10];
    const float* loc_wnj = (const float*)d_in[11];
    const float* loc_we  = (const float*)d_in[12];
    const float* loc_attn= (const float*)d_in[13];
    const float* loc_wnode=(const float*)d_in[14];
    const float* agg1_w  = (const float*)d_in[15];
    const float* agg1_b  = (const float*)d_in[16];
    const float* glob_wni= (const float*)d_in[17];
    const float* glob_wnj= (const float*)d_in[18];
    const float* glob_we = (const float*)d_in[19];
    const float* glob_attn=(const float*)d_in[20];
    const float* glob_wnode=(const float*)d_in[21];
    const float* agg2_w  = (const float*)d_in[22];
    const float* agg2_b  = (const float*)d_in[23];
    const float* w1_ui   = (const float*)d_in[24];
    const float* b1_ui   = (const float*)d_in[25];
    const float* w1_sg   = (const float*)d_in[26];
    const float* b1_sg   = (const float*)d_in[27];
    const float* w2_ui   = (const float*)d_in[28];
    const float* b2_ui   = (const float*)d_in[29];
    const float* w2_sg   = (const float*)d_in[30];
    const float* b2_sg   = (const float*)d_in[31];

    // workspace carve (all offsets 256B-aligned)
    char* wsp = (char*)d_ws;
    auto carve = [&](size_t bytes) { char* p = wsp; wsp += (bytes + 255) & ~(size_t)255; return p; };
    ushort* zb    = (ushort*)carve((size_t)NN * 256 * 2);
    ushort* hb[5];
    for (int i = 0; i < 5; i++) hb[i] = (ushort*)carve((size_t)NN * 64 * 2);
    float*  scv   = (float*)carve((size_t)NE * 16);
    float*  m1p   = (float*)carve((size_t)NE * 4);
    float*  m2p   = (float*)carve((size_t)NE * 4);
    int*    srcp  = (int*)carve((size_t)NE * 4);
    int*    eidx  = (int*)carve((size_t)NE * 4);
    ushort* Bsc   = (ushort*)carve(4 * 24576 * 2);
    ushort* Bfold = (ushort*)carve(4 * 16384 * 2);
    int* deg      = (int*)carve(NN * 4);
    int* rowptr   = (int*)carve((NN + 4) * 4);
    int* partials = (int*)carve(256 * 4);

    // ---- weight prep (state-independent) + deterministic CSR build ----
    k_prep_score_all<<<384, 256, 0, stream>>>(loc_we, glob_we, loc_wni, glob_wni,
                                              loc_wnj, glob_wnj, Bsc);
    k_fold_all<<<256, 256, 0, stream>>>(loc_wnode, agg1_w, glob_wnode, agg2_w, Bfold);
    hipMemsetAsync(deg, 0, NN * sizeof(int), stream);
    k_count<<<1280, 256, 0, stream>>>(dst, deg, NE);
    scan_local<<<196, 256, 0, stream>>>(deg, rowptr, partials, NN);
    scan_partials<<<1, 256, 0, stream>>>(partials, 196);
    scan_add<<<196, 256, 0, stream>>>(rowptr, partials, NN, NE);
    hipMemsetAsync(deg, 0, NN * sizeof(int), stream);
    k_scatter<<<1280, 256, 0, stream>>>(dst, rowptr, deg, eidx, NE);
    k_sort_buckets<<<196, 256, 0, stream>>>(rowptr, eidx, NN);
    k_perm_small<<<1250, 256, 0, stream>>>(eidx, src, mask1, mask2,
                                           srcp, m1p, m2p, NE);
    k_cvt<<<3200, 256, 0, stream>>>(x, hb[0], NN * 64);

    auto egat = [&](const ushort* hin, int e, const float* maskp, const float* attn,
                    const float* aggb, int act, ushort* hout) {
        int is_glob = e & 1;
        if (is_glob)
            score32<1><<<1250, 512, 0, stream>>>(efeat2, Bsc + e * 24576, hin,
                                                 src, dst, attn, scv);
        else
            score32<0><<<1250, 512, 0, stream>>>(efeat, Bsc + e * 24576, hin,
                                                 src, dst, attn, scv);
        node_fused<<<NN / 16, 256, 0, stream>>>(scv, eidx, rowptr, srcp, maskp, hin, zb);
        gemm_agg<<<782, 256, 0, stream>>>(zb, NN, Bfold + e * 16384, aggb, act, hout);
    };

    egat(hb[0], 0, m1p, loc_attn,        agg1_b,      0, hb[1]);
    egat(hb[1], 1, m2p, glob_attn,       agg2_b,      1, hb[2]);
    egat(hb[2], 2, m1p, loc_attn + 128,  agg1_b + 64, 0, hb[3]);
    egat(hb[3], 3, m2p, glob_attn + 128, agg2_b + 64, 1, hb[4]);

    float* out = (float*)d_out;
    final_sg<<<BATCH / 4, 256, 0, stream>>>(hb[2], hb[4], gidx, w1_sg, b1_sg, w2_sg, b2_sg, out);
    final_ui<<<BATCH / 4, 256, 0, stream>>>(hb[1], hb[3], uidx, iidx, w1_ui, b1_ui, w2_ui, b2_ui, out + BATCH);
}